// Round 1
// baseline (574.545 us; speedup 1.0000x reference)
//
#include <hip/hip_runtime.h>
#include <hip/hip_bf16.h>
#include <cfloat>

// Problem constants (fixed by the reference file)
#define NN 4096
#define DD 256
#define MM 5
#define K_INTRA 21   // top_k + 1 (drop first = self)
#define K_INTER 10
#define K_TOT 30     // 20 + 10

// ---------------------------------------------------------------------------
// Kernel 1: sim = E @ E^T in fp64 (fp32 inputs converted at LDS store).
// 64x64 tile, 16x16 threads, 4x4 micro-tile per thread.
// StoreT = double (big-ws path, exact ordering) or float (fallback into d_out).
// ---------------------------------------------------------------------------
template <typename StoreT>
__global__ __launch_bounds__(256) void gemm_ee(const float* __restrict__ E,
                                               StoreT* __restrict__ out) {
    __shared__ double As[16][66];  // [k][row], pad 66 keeps 16B align + spreads banks
    __shared__ double Bs[16][66];  // [k][col]

    const int tx = threadIdx.x;            // 0..15
    const int ty = threadIdx.y;            // 0..15
    const int tid = ty * 16 + tx;          // 0..255
    const int rowBase = blockIdx.y * 64;
    const int colBase = blockIdx.x * 64;

    const int lr = tid >> 2;               // 0..63 : tile row/col this thread stages
    const int lq = (tid & 3) * 4;          // 0,4,8,12 : k-offset of its float4

    double acc[4][4] = {};

    for (int kc = 0; kc < DD; kc += 16) {
        const float4 a4 = *(const float4*)(E + (size_t)(rowBase + lr) * DD + kc + lq);
        const float4 b4 = *(const float4*)(E + (size_t)(colBase + lr) * DD + kc + lq);
        As[lq + 0][lr] = (double)a4.x;
        As[lq + 1][lr] = (double)a4.y;
        As[lq + 2][lr] = (double)a4.z;
        As[lq + 3][lr] = (double)a4.w;
        Bs[lq + 0][lr] = (double)b4.x;
        Bs[lq + 1][lr] = (double)b4.y;
        Bs[lq + 2][lr] = (double)b4.z;
        Bs[lq + 3][lr] = (double)b4.w;
        __syncthreads();
#pragma unroll
        for (int k = 0; k < 16; ++k) {
            double a0 = As[k][ty * 4 + 0];
            double a1 = As[k][ty * 4 + 1];
            double a2 = As[k][ty * 4 + 2];
            double a3 = As[k][ty * 4 + 3];
            double b0 = Bs[k][tx * 4 + 0];
            double b1 = Bs[k][tx * 4 + 1];
            double b2 = Bs[k][tx * 4 + 2];
            double b3 = Bs[k][tx * 4 + 3];
            acc[0][0] = fma(a0, b0, acc[0][0]);
            acc[0][1] = fma(a0, b1, acc[0][1]);
            acc[0][2] = fma(a0, b2, acc[0][2]);
            acc[0][3] = fma(a0, b3, acc[0][3]);
            acc[1][0] = fma(a1, b0, acc[1][0]);
            acc[1][1] = fma(a1, b1, acc[1][1]);
            acc[1][2] = fma(a1, b2, acc[1][2]);
            acc[1][3] = fma(a1, b3, acc[1][3]);
            acc[2][0] = fma(a2, b0, acc[2][0]);
            acc[2][1] = fma(a2, b1, acc[2][1]);
            acc[2][2] = fma(a2, b2, acc[2][2]);
            acc[2][3] = fma(a2, b3, acc[2][3]);
            acc[3][0] = fma(a3, b0, acc[3][0]);
            acc[3][1] = fma(a3, b1, acc[3][1]);
            acc[3][2] = fma(a3, b2, acc[3][2]);
            acc[3][3] = fma(a3, b3, acc[3][3]);
        }
        __syncthreads();
    }

#pragma unroll
    for (int m = 0; m < 4; ++m) {
        const size_t r = (size_t)(rowBase + ty * 4 + m) * NN + colBase + tx * 4;
#pragma unroll
        for (int n = 0; n < 4; ++n) out[r + n] = (StoreT)acc[m][n];
    }
}

// ---------------------------------------------------------------------------
// Kernel 2: per-row masked top-k via iterative argmax.
// One block (256 threads) per row. Row lives in LDS as fp64.
// Tie-break: lower index first (jax.lax.top_k semantics). Consumed entries
// are marked -DBL_MAX, which exactly reproduces lax.top_k ordering even if
// ties among the -1e30 mask values ever mattered.
// ---------------------------------------------------------------------------
template <typename SimT>
__global__ __launch_bounds__(256) void topk_rows(const SimT* __restrict__ sim,
                                                 const int* __restrict__ batch,
                                                 int* __restrict__ knn) {
    __shared__ double work[NN];
    __shared__ double wv[4];
    __shared__ int wi[4];
    __shared__ int winners[K_INTRA];

    const int i = blockIdx.x;
    const int t = threadIdx.x;
    const int bi = batch[i];
    const double NEGV = -1e30;

    unsigned smask = 0;  // per-thread bitmask: same-batch for its 16 strided elems
#pragma unroll
    for (int s = 0; s < 16; ++s) {
        const int j = t + s * 256;
        const double v = (double)sim[(size_t)i * NN + j];
        const bool same = (batch[j] == bi);
        smask |= (same ? 1u : 0u) << s;
        work[j] = same ? v : NEGV;
    }
    __syncthreads();

    // ---- phase 1: intra top-21 ----
    for (int q = 0; q < K_INTRA; ++q) {
        double bv = -DBL_MAX;
        int bj = 1 << 30;
#pragma unroll
        for (int s = 0; s < 16; ++s) {
            const int j = t + s * 256;  // ascending j -> strict > keeps lowest idx
            const double v = work[j];
            if (v > bv) { bv = v; bj = j; }
        }
        // wave reduce (64 lanes), lower-index tie-break
        for (int off = 32; off; off >>= 1) {
            const double ov = __shfl_down(bv, off);
            const int oj = __shfl_down(bj, off);
            if (ov > bv || (ov == bv && oj < bj)) { bv = ov; bj = oj; }
        }
        if ((t & 63) == 0) { wv[t >> 6] = bv; wi[t >> 6] = bj; }
        __syncthreads();
        if (t == 0) {
            double fv = wv[0];
            int fj = wi[0];
#pragma unroll
            for (int w = 1; w < 4; ++w)
                if (wv[w] > fv || (wv[w] == fv && wi[w] < fj)) { fv = wv[w]; fj = wi[w]; }
            winners[q] = fj;
            work[fj] = -DBL_MAX;  // consume
        }
        __syncthreads();
    }
    if (t < K_INTRA - 1) knn[i * K_TOT + t] = winners[t + 1];  // drop first (=self)

    // ---- phase 2: inter top-10 (rebuild with inverted mask) ----
#pragma unroll
    for (int s = 0; s < 16; ++s) {
        const int j = t + s * 256;
        const double v = (double)sim[(size_t)i * NN + j];
        const bool same = (smask >> s) & 1u;
        work[j] = same ? NEGV : v;
    }
    __syncthreads();
    for (int q = 0; q < K_INTER; ++q) {
        double bv = -DBL_MAX;
        int bj = 1 << 30;
#pragma unroll
        for (int s = 0; s < 16; ++s) {
            const int j = t + s * 256;
            const double v = work[j];
            if (v > bv) { bv = v; bj = j; }
        }
        for (int off = 32; off; off >>= 1) {
            const double ov = __shfl_down(bv, off);
            const int oj = __shfl_down(bj, off);
            if (ov > bv || (ov == bv && oj < bj)) { bv = ov; bj = oj; }
        }
        if ((t & 63) == 0) { wv[t >> 6] = bv; wi[t >> 6] = bj; }
        __syncthreads();
        if (t == 0) {
            double fv = wv[0];
            int fj = wi[0];
#pragma unroll
            for (int w = 1; w < 4; ++w)
                if (wv[w] > fv || (wv[w] == fv && wi[w] < fj)) { fv = wv[w]; fj = wi[w]; }
            winners[q] = fj;
            work[fj] = -DBL_MAX;
        }
        __syncthreads();
    }
    if (t < K_INTER) knn[i * K_TOT + 20 + t] = winners[t];
}

// ---------------------------------------------------------------------------
// Kernel 3: mutuality + sparse locality scatter + all_close.
// locality region was zeroed by hipMemsetAsync; only mutual pairs written.
// ---------------------------------------------------------------------------
__global__ __launch_bounds__(256) void finalize_k(const int* __restrict__ knn,
                                                  const float* __restrict__ adj,
                                                  const int* __restrict__ cl,
                                                  float* __restrict__ out) {
    const int gid = blockIdx.x * 256 + threadIdx.x;
    if (gid >= NN * K_TOT) return;
    const int i = gid / K_TOT;
    const int j = knn[gid];

    bool mutual = false;
#pragma unroll
    for (int s = 0; s < K_TOT; ++s) mutual |= (knn[j * K_TOT + s] == i);

    if (mutual) out[(size_t)i * NN + j] = adj[(size_t)i * NN + j];

    bool ac = mutual;
    if (!ac) {
        bool alleq = true;
#pragma unroll
        for (int m = 0; m < MM; ++m) alleq &= (cl[m * NN + i] == cl[m * NN + j]);
        ac = alleq;
    }
    out[(size_t)NN * NN + gid] = ac ? 1.0f : 0.0f;
}

// ---------------------------------------------------------------------------
extern "C" void kernel_launch(void* const* d_in, const int* in_sizes, int n_in,
                              void* d_out, int out_size, void* d_ws, size_t ws_size,
                              hipStream_t stream) {
    const float* adj = (const float*)d_in[0];
    const float* enc = (const float*)d_in[1];
    const int* batch = (const int*)d_in[2];
    const int* cl = (const int*)d_in[3];
    float* out = (float*)d_out;

    const size_t simBytes = (size_t)NN * NN * sizeof(double);   // 134.2 MB
    const size_t knnBytes = (size_t)NN * K_TOT * sizeof(int);   // 0.49 MB
    const bool big = ws_size >= simBytes + knnBytes;

    if (big) {
        // exact-ordering path: fp64 sims in workspace
        double* simd = (double*)d_ws;
        int* knn = (int*)((char*)d_ws + simBytes);
        gemm_ee<double><<<dim3(NN / 64, NN / 64), dim3(16, 16), 0, stream>>>(enc, simd);
        topk_rows<double><<<NN, 256, 0, stream>>>(simd, batch, knn);
        hipMemsetAsync(d_out, 0, (size_t)NN * NN * sizeof(float), stream);
        finalize_k<<<(NN * K_TOT + 255) / 256, 256, 0, stream>>>(knn, adj, cl, out);
    } else {
        // fallback: fp32 sims staged in the (later overwritten) locality region
        float* simf = out;
        int* knn = (int*)d_ws;
        gemm_ee<float><<<dim3(NN / 64, NN / 64), dim3(16, 16), 0, stream>>>(enc, simf);
        topk_rows<float><<<NN, 256, 0, stream>>>(simf, batch, knn);
        hipMemsetAsync(d_out, 0, (size_t)NN * NN * sizeof(float), stream);
        finalize_k<<<(NN * K_TOT + 255) / 256, 256, 0, stream>>>(knn, adj, cl, out);
    }
}

// Round 2
// 483.657 us; speedup vs baseline: 1.1879x; 1.1879x over previous
//
#include <hip/hip_runtime.h>
#include <hip/hip_bf16.h>
#include <cfloat>

// Problem constants (fixed by the reference file)
#define NN 4096
#define DD 256
#define MM 5
#define K_INTRA 21   // top_k + 1 (drop first = self)
#define K_INTER 10
#define K_TOT 30     // 20 + 10

// ---------------------------------------------------------------------------
// Kernel 1: sim = E @ E^T in fp64 (fp32 inputs converted at LDS store).
// Symmetric: only upper-triangular 64x64 blocks computed (bx >= by); each
// off-diagonal block stores its tile AND the mirrored transpose tile.
// 64x64 tile, 16x16 threads, 4x4 micro-tile per thread.
// ---------------------------------------------------------------------------
template <typename StoreT>
__global__ __launch_bounds__(256) void gemm_ee(const float* __restrict__ E,
                                               StoreT* __restrict__ out) {
    if (blockIdx.x < blockIdx.y) return;  // lower triangle: mirrored by upper

    __shared__ double As[16][66];  // [k][row] (66: 16B-aligned rows, bank spread)
    __shared__ double Bs[16][66];  // [k][col]

    const int tx = threadIdx.x;            // 0..15
    const int ty = threadIdx.y;            // 0..15
    const int tid = ty * 16 + tx;          // 0..255
    const int rowBase = blockIdx.y * 64;
    const int colBase = blockIdx.x * 64;

    const int lr = tid >> 2;               // 0..63 : tile row/col this thread stages
    const int lq = (tid & 3) * 4;          // 0,4,8,12 : k-offset of its float4

    double acc[4][4] = {};

    for (int kc = 0; kc < DD; kc += 16) {
        const float4 a4 = *(const float4*)(E + (size_t)(rowBase + lr) * DD + kc + lq);
        const float4 b4 = *(const float4*)(E + (size_t)(colBase + lr) * DD + kc + lq);
        As[lq + 0][lr] = (double)a4.x;
        As[lq + 1][lr] = (double)a4.y;
        As[lq + 2][lr] = (double)a4.z;
        As[lq + 3][lr] = (double)a4.w;
        Bs[lq + 0][lr] = (double)b4.x;
        Bs[lq + 1][lr] = (double)b4.y;
        Bs[lq + 2][lr] = (double)b4.z;
        Bs[lq + 3][lr] = (double)b4.w;
        __syncthreads();
#pragma unroll
        for (int k = 0; k < 16; ++k) {
            const double2* Ap = (const double2*)(&As[k][ty * 4]);
            const double2* Bp = (const double2*)(&Bs[k][tx * 4]);
            const double2 a01 = Ap[0], a23 = Ap[1];
            const double2 b01 = Bp[0], b23 = Bp[1];
            const double a[4] = {a01.x, a01.y, a23.x, a23.y};
            const double b[4] = {b01.x, b01.y, b23.x, b23.y};
#pragma unroll
            for (int m = 0; m < 4; ++m)
#pragma unroll
                for (int n = 0; n < 4; ++n)
                    acc[m][n] = fma(a[m], b[n], acc[m][n]);
        }
        __syncthreads();
    }

    // normal store: rows rowBase+ty*4+m, cols colBase+tx*4+n
#pragma unroll
    for (int m = 0; m < 4; ++m) {
        const size_t r = (size_t)(rowBase + ty * 4 + m) * NN + colBase + tx * 4;
#pragma unroll
        for (int n = 0; n < 4; ++n) out[r + n] = (StoreT)acc[m][n];
    }
    // mirrored store for off-diagonal blocks: (c, r) <- acc[m][n] transposed
    if (blockIdx.x > blockIdx.y) {
#pragma unroll
        for (int n = 0; n < 4; ++n) {
            const size_t r = (size_t)(colBase + tx * 4 + n) * NN + rowBase + ty * 4;
#pragma unroll
            for (int m = 0; m < 4; ++m) out[r + m] = (StoreT)acc[m][n];
        }
    }
}

// ---------------------------------------------------------------------------
// Kernel 2: per-row masked top-k, register-resident iterative argmax.
// One block (256 threads) per row; each thread owns 16 elements in registers
// (j = s*512 + t*2 + e, ascending within thread). Per round: wave shuffle
// argmax + 4-slot LDS block merge; only the winning thread rescans its 16
// registers. Tie-break: lower index (jax.lax.top_k semantics); consumed
// entries -> dead bit (acts as -inf).
// ---------------------------------------------------------------------------
template <typename SimT>
__global__ __launch_bounds__(256) void topk_rows(const SimT* __restrict__ sim,
                                                 const int* __restrict__ batch,
                                                 int* __restrict__ knn) {
    __shared__ double wv[4];
    __shared__ int wi[4];

    const int i = blockIdx.x;
    const int t = threadIdx.x;
    const int bi = batch[i];
    const double NEGV = -1e30;

    // load 16 elements + batch mask into registers (coalesced 16B chunks)
    double v[16];
    unsigned smask = 0;
#pragma unroll
    for (int s = 0; s < 8; ++s) {
        const int j0 = s * 512 + t * 2;
        const SimT* p = sim + (size_t)i * NN + j0;
        v[s * 2 + 0] = (double)p[0];
        v[s * 2 + 1] = (double)p[1];
        const int2 b2 = *(const int2*)(batch + j0);
        smask |= (b2.x == bi ? 1u : 0u) << (s * 2 + 0);
        smask |= (b2.y == bi ? 1u : 0u) << (s * 2 + 1);
    }

    unsigned dead = 0;

    // ---- phase 1: intra top-21 (drop first = self) ----
    double lv = -DBL_MAX;
    int lj = 1 << 30;
#pragma unroll
    for (int u = 0; u < 16; ++u) {
        const int j = (u >> 1) * 512 + t * 2 + (u & 1);  // ascending in u
        const double val = ((smask >> u) & 1u) ? v[u] : NEGV;
        if (val > lv) { lv = val; lj = j; }
    }

    for (int q = 0; q < K_INTRA; ++q) {
        // wave reduce (64 lanes), lower-index tie-break
        double bv = lv;
        int bj = lj;
        for (int off = 32; off; off >>= 1) {
            const double ov = __shfl_down(bv, off);
            const int oj = __shfl_down(bj, off);
            if (ov > bv || (ov == bv && oj < bj)) { bv = ov; bj = oj; }
        }
        if ((t & 63) == 0) { wv[t >> 6] = bv; wi[t >> 6] = bj; }
        __syncthreads();
        double fv = wv[0];
        int fj = wi[0];
#pragma unroll
        for (int w = 1; w < 4; ++w)
            if (wv[w] > fv || (wv[w] == fv && wi[w] < fj)) { fv = wv[w]; fj = wi[w]; }
        if (t == 0 && q > 0) knn[i * K_TOT + q - 1] = fj;
        if (t == ((fj & 511) >> 1)) {  // owner invalidates + rescans
            const int u = ((fj >> 9) << 1) | (fj & 1);
            dead |= 1u << u;
            lv = -DBL_MAX;
            lj = 1 << 30;
#pragma unroll
            for (int uu = 0; uu < 16; ++uu) {
                const int j = (uu >> 1) * 512 + t * 2 + (uu & 1);
                const double val = ((dead >> uu) & 1u)
                                       ? -DBL_MAX
                                       : (((smask >> uu) & 1u) ? v[uu] : NEGV);
                if (val > lv) { lv = val; lj = j; }
            }
        }
        __syncthreads();  // protect wv/wi for next round
    }

    // ---- phase 2: inter top-10 (inverted mask, fresh state) ----
    dead = 0;
    lv = -DBL_MAX;
    lj = 1 << 30;
#pragma unroll
    for (int u = 0; u < 16; ++u) {
        const int j = (u >> 1) * 512 + t * 2 + (u & 1);
        const double val = ((smask >> u) & 1u) ? NEGV : v[u];
        if (val > lv) { lv = val; lj = j; }
    }

    for (int q = 0; q < K_INTER; ++q) {
        double bv = lv;
        int bj = lj;
        for (int off = 32; off; off >>= 1) {
            const double ov = __shfl_down(bv, off);
            const int oj = __shfl_down(bj, off);
            if (ov > bv || (ov == bv && oj < bj)) { bv = ov; bj = oj; }
        }
        if ((t & 63) == 0) { wv[t >> 6] = bv; wi[t >> 6] = bj; }
        __syncthreads();
        double fv = wv[0];
        int fj = wi[0];
#pragma unroll
        for (int w = 1; w < 4; ++w)
            if (wv[w] > fv || (wv[w] == fv && wi[w] < fj)) { fv = wv[w]; fj = wi[w]; }
        if (t == 0) knn[i * K_TOT + 20 + q] = fj;
        if (t == ((fj & 511) >> 1)) {
            const int u = ((fj >> 9) << 1) | (fj & 1);
            dead |= 1u << u;
            lv = -DBL_MAX;
            lj = 1 << 30;
#pragma unroll
            for (int uu = 0; uu < 16; ++uu) {
                const int j = (uu >> 1) * 512 + t * 2 + (uu & 1);
                const double val = ((dead >> uu) & 1u)
                                       ? -DBL_MAX
                                       : (((smask >> uu) & 1u) ? NEGV : v[uu]);
                if (val > lv) { lv = val; lj = j; }
            }
        }
        __syncthreads();
    }
}

// ---------------------------------------------------------------------------
// Kernel 3: mutuality + sparse locality scatter + all_close.
// locality region was zeroed by hipMemsetAsync; only mutual pairs written.
// ---------------------------------------------------------------------------
__global__ __launch_bounds__(256) void finalize_k(const int* __restrict__ knn,
                                                  const float* __restrict__ adj,
                                                  const int* __restrict__ cl,
                                                  float* __restrict__ out) {
    const int gid = blockIdx.x * 256 + threadIdx.x;
    if (gid >= NN * K_TOT) return;
    const int i = gid / K_TOT;
    const int j = knn[gid];

    bool mutual = false;
#pragma unroll
    for (int s = 0; s < K_TOT; ++s) mutual |= (knn[j * K_TOT + s] == i);

    if (mutual) out[(size_t)i * NN + j] = adj[(size_t)i * NN + j];

    bool ac = mutual;
    if (!ac) {
        bool alleq = true;
#pragma unroll
        for (int m = 0; m < MM; ++m) alleq &= (cl[m * NN + i] == cl[m * NN + j]);
        ac = alleq;
    }
    out[(size_t)NN * NN + gid] = ac ? 1.0f : 0.0f;
}

// ---------------------------------------------------------------------------
extern "C" void kernel_launch(void* const* d_in, const int* in_sizes, int n_in,
                              void* d_out, int out_size, void* d_ws, size_t ws_size,
                              hipStream_t stream) {
    const float* adj = (const float*)d_in[0];
    const float* enc = (const float*)d_in[1];
    const int* batch = (const int*)d_in[2];
    const int* cl = (const int*)d_in[3];
    float* out = (float*)d_out;

    const size_t simBytes = (size_t)NN * NN * sizeof(double);   // 134.2 MB
    const size_t knnBytes = (size_t)NN * K_TOT * sizeof(int);   // 0.49 MB
    const bool big = ws_size >= simBytes + knnBytes;

    if (big) {
        // exact-ordering path: fp64 sims in workspace
        double* simd = (double*)d_ws;
        int* knn = (int*)((char*)d_ws + simBytes);
        gemm_ee<double><<<dim3(NN / 64, NN / 64), dim3(16, 16), 0, stream>>>(enc, simd);
        topk_rows<double><<<NN, 256, 0, stream>>>(simd, batch, knn);
        hipMemsetAsync(d_out, 0, (size_t)NN * NN * sizeof(float), stream);
        finalize_k<<<(NN * K_TOT + 255) / 256, 256, 0, stream>>>(knn, adj, cl, out);
    } else {
        // fallback: fp32 sims staged in the (later overwritten) locality region
        float* simf = out;
        int* knn = (int*)d_ws;
        gemm_ee<float><<<dim3(NN / 64, NN / 64), dim3(16, 16), 0, stream>>>(enc, simf);
        topk_rows<float><<<NN, 256, 0, stream>>>(simf, batch, knn);
        hipMemsetAsync(d_out, 0, (size_t)NN * NN * sizeof(float), stream);
        finalize_k<<<(NN * K_TOT + 255) / 256, 256, 0, stream>>>(knn, adj, cl, out);
    }
}

// Round 3
// 313.433 us; speedup vs baseline: 1.8331x; 1.5431x over previous
//
#include <hip/hip_runtime.h>
#include <hip/hip_bf16.h>
#include <cfloat>

// Problem constants (fixed by the reference file)
#define NN 4096
#define DD 256
#define MM 5
#define K_TOT 30       // 20 intra + 10 inter
#define TGT_INTRA 32   // capture >= 32 intra candidates (need top-21 incl self)
#define TGT_INTER 24   // capture >= 24 inter candidates (need top-10)
#define CAND_CAP 64

// ---------------------------------------------------------------------------
// Kernel 1: sim = E @ E^T in fp32, symmetric (bx >= by only, mirror store).
// 128x128 tile, 16x16 threads, 8x8 micro-tile. fp32 accuracy only feeds
// candidate selection (margins >> 1e-4); exact ordering comes from K2's
// fp64 rescore.
// ---------------------------------------------------------------------------
__global__ __launch_bounds__(256) void gemm_f32(const float* __restrict__ E,
                                                float* __restrict__ out) {
    const int bx = blockIdx.x, by = blockIdx.y;
    if (bx < by) return;  // lower triangle comes from mirror

    __shared__ float As[16][132];  // [k][row], 132*4B row pitch (16B-aligned)
    __shared__ float Bs[16][132];  // [k][col]

    const int tx = threadIdx.x, ty = threadIdx.y;
    const int tid = ty * 16 + tx;
    const int rowBase = by * 128, colBase = bx * 128;

    float acc[8][8] = {};

    for (int kc = 0; kc < DD; kc += 16) {
#pragma unroll
        for (int q = 0; q < 2; ++q) {
            const int idx = tid * 2 + q;      // 0..511
            const int row = idx >> 2;         // 0..127
            const int kq = (idx & 3) * 4;     // 0,4,8,12
            const float4 a4 = *(const float4*)(E + (size_t)(rowBase + row) * DD + kc + kq);
            const float4 b4 = *(const float4*)(E + (size_t)(colBase + row) * DD + kc + kq);
            As[kq + 0][row] = a4.x; As[kq + 1][row] = a4.y;
            As[kq + 2][row] = a4.z; As[kq + 3][row] = a4.w;
            Bs[kq + 0][row] = b4.x; Bs[kq + 1][row] = b4.y;
            Bs[kq + 2][row] = b4.z; Bs[kq + 3][row] = b4.w;
        }
        __syncthreads();
#pragma unroll
        for (int k = 0; k < 16; ++k) {
            float a[8], b[8];
            *(float4*)&a[0] = *(const float4*)&As[k][ty * 8];
            *(float4*)&a[4] = *(const float4*)&As[k][ty * 8 + 4];
            *(float4*)&b[0] = *(const float4*)&Bs[k][tx * 8];
            *(float4*)&b[4] = *(const float4*)&Bs[k][tx * 8 + 4];
#pragma unroll
            for (int m = 0; m < 8; ++m)
#pragma unroll
                for (int n = 0; n < 8; ++n)
                    acc[m][n] = fmaf(a[m], b[n], acc[m][n]);
        }
        __syncthreads();
    }

#pragma unroll
    for (int m = 0; m < 8; ++m) {
        float* p = out + (size_t)(rowBase + ty * 8 + m) * NN + colBase + tx * 8;
        *(float4*)(p + 0) = make_float4(acc[m][0], acc[m][1], acc[m][2], acc[m][3]);
        *(float4*)(p + 4) = make_float4(acc[m][4], acc[m][5], acc[m][6], acc[m][7]);
    }
    if (bx > by) {  // mirror: sim(col,row) = sim(row,col)
#pragma unroll
        for (int n = 0; n < 8; ++n) {
            float* p = out + (size_t)(colBase + tx * 8 + n) * NN + rowBase + ty * 8;
#pragma unroll
            for (int m = 0; m < 8; ++m) p[m] = acc[m][n];
        }
    }
}

// ---------------------------------------------------------------------------
// Kernel 2 (fused): per-row candidate selection via key histogram, fp64
// rescore of candidates, ordered top-21/top-10 within single waves.
// Block = 256 threads = one row. No serial top-k over the 4096 elements.
// ---------------------------------------------------------------------------
__device__ __forceinline__ unsigned f32_sortable(float f) {
    unsigned u = __float_as_uint(f);
    return (u & 0x80000000u) ? ~u : (u | 0x80000000u);  // monotone: bigger f -> bigger key
}

__global__ __launch_bounds__(256) void select_rescore(const float* __restrict__ sim,
                                                      const float* __restrict__ E,
                                                      const int* __restrict__ batch,
                                                      int* __restrict__ knn) {
    __shared__ unsigned hist[2][2048];     // 16 KB: coarse bins = key >> 21
    __shared__ unsigned subhist[2][64];    // refine bins = (key >> 15) & 63
    __shared__ int Tc[2];                  // coarse threshold bin
    __shared__ unsigned remc[2];           // remaining count for refine
    __shared__ unsigned thrKey[2];         // final key threshold
    __shared__ int candIdx[2][CAND_CAP];
    __shared__ double candVal[2][CAND_CAP];
    __shared__ int cnt[2];
    __shared__ float4 Ei4[DD / 4];         // this row's embedding (fp32)

    const int i = blockIdx.x;
    const int t = threadIdx.x;
    const int lane = t & 63;
    const int w = t >> 6;
    const int bi = batch[i];

    // ---- init ----
#pragma unroll
    for (int s = 0; s < 16; ++s) ((unsigned*)hist)[t + s * 256] = 0u;
    if (t < 128) ((unsigned*)subhist)[t] = 0u;
    if (t < 128) ((int*)candIdx)[t] = 0x7FFFFFFF;
    if (t < 2) cnt[t] = 0;
    if (t < 2) { Tc[t] = 0; remc[t] = 1u; }
    if (t < DD / 4) Ei4[t] = ((const float4*)(E + (size_t)i * DD))[t];
    __syncthreads();

    // ---- pass 1: keys + masks + coarse histogram ----
    // element mapping: j = q*1024 + t*4 + c  (fully coalesced float4/int4)
    unsigned key[16];
    unsigned mmask = 0;  // bit u set => element u is INTER (batch differs)
    const float* simRow = sim + (size_t)i * NN;
#pragma unroll
    for (int q = 0; q < 4; ++q) {
        const int j0 = q * 1024 + t * 4;
        float fv[4];
        int bv[4];
        *(float4*)fv = *(const float4*)(simRow + j0);
        *(int4*)bv = *(const int4*)(batch + j0);
#pragma unroll
        for (int c = 0; c < 4; ++c) {
            const unsigned k = f32_sortable(fv[c]);
            const int u = q * 4 + c;
            key[u] = k;
            const int m = (bv[c] == bi) ? 0 : 1;
            mmask |= (unsigned)m << u;
            atomicAdd(&hist[m][k >> 21], 1u);
        }
    }
    __syncthreads();

    // ---- pass 2: coarse threshold (wave 0 -> intra, wave 1 -> inter) ----
    if (w < 2) {
        const int m = w;
        const unsigned target = (m == 0) ? TGT_INTRA : TGT_INTER;
        const int base = (63 - lane) * 32;  // lane 0 owns the TOP chunk
        unsigned s = 0;
#pragma unroll
        for (int b = 0; b < 32; ++b) s += hist[m][base + b];
        unsigned cum = s;  // inclusive scan from lane 0 (top) downward
        for (int off = 1; off < 64; off <<= 1) {
            const unsigned o = __shfl_up(cum, off);
            if (lane >= off) cum += o;
        }
        if (cum >= target && (cum - s) < target) {  // unique crossing lane
            unsigned excl = cum - s;  // count of bins above this chunk
            for (int b = base + 31; b >= base; --b) {
                const unsigned h = hist[m][b];
                excl += h;
                if (excl >= target) {
                    Tc[m] = b;
                    remc[m] = target - (excl - h);  // >= 1
                    break;
                }
            }
        }
    }
    __syncthreads();

    // ---- pass 2b: sub-histogram of the crossing bin ----
    const int T0 = Tc[0], T1 = Tc[1];
#pragma unroll
    for (int u = 0; u < 16; ++u) {
        const int m = (mmask >> u) & 1;
        const int T = m ? T1 : T0;
        if ((int)(key[u] >> 21) == T) atomicAdd(&subhist[m][(key[u] >> 15) & 63], 1u);
    }
    __syncthreads();

    // ---- pass 2c: refine threshold within the crossing bin ----
    if (w < 2) {
        const int m = w;
        const unsigned target2 = remc[m];
        const unsigned s = subhist[m][63 - lane];  // lane 0 = top sub-bin
        unsigned cum = s;
        for (int off = 1; off < 64; off <<= 1) {
            const unsigned o = __shfl_up(cum, off);
            if (lane >= off) cum += o;
        }
        if (cum >= target2 && (cum - s) < target2)
            thrKey[m] = ((unsigned)Tc[m] << 21) | ((unsigned)(63 - lane) << 15);
    }
    __syncthreads();

    // ---- pass 3: collect candidate indices ----
    const unsigned thr0 = thrKey[0], thr1 = thrKey[1];
#pragma unroll
    for (int q = 0; q < 4; ++q) {
#pragma unroll
        for (int c = 0; c < 4; ++c) {
            const int u = q * 4 + c;
            const int m = (mmask >> u) & 1;
            if (key[u] >= (m ? thr1 : thr0)) {
                const int pos = atomicAdd(&cnt[m], 1);
                if (pos < CAND_CAP) candIdx[m][pos] = q * 1024 + t * 4 + c;
            }
        }
    }
    __syncthreads();

    // ---- pass 4: fp64 rescore of candidates (threads 0..127) ----
    if (t < 128) {
        const int m = t >> 6;
        const int slot = t & 63;
        const int c = min(cnt[m], CAND_CAP);
        double val = -DBL_MAX;
        if (slot < c) {
            const int j = candIdx[m][slot];
            const float* ej = E + (size_t)j * DD;
            const float* ei = (const float*)Ei4;
            double a0 = 0, a1 = 0, a2 = 0, a3 = 0;
#pragma unroll 8
            for (int k = 0; k < DD; k += 4) {
                const float4 e = *(const float4*)(ej + k);
                a0 = fma((double)ei[k + 0], (double)e.x, a0);
                a1 = fma((double)ei[k + 1], (double)e.y, a1);
                a2 = fma((double)ei[k + 2], (double)e.z, a2);
                a3 = fma((double)ei[k + 3], (double)e.w, a3);
            }
            val = (a0 + a1) + (a2 + a3);
        }
        candVal[m][slot] = val;
    }
    __syncthreads();

    // ---- pass 5: ordered selection, wave 0 = intra(21, drop rank0),
    //              wave 1 = inter(10). Pure intra-wave, runs concurrently. ----
    if (w < 2) {
        const int m = w;
        double val = candVal[m][lane];
        int idx = candIdx[m][lane];
        const int rounds = (m == 0) ? 21 : 10;
        for (int q = 0; q < rounds; ++q) {
            double tv = val;
            int ti = idx;
#pragma unroll
            for (int off = 32; off; off >>= 1) {  // xor butterfly: all lanes get winner
                const double ov = __shfl_xor(tv, off);
                const int oi = __shfl_xor(ti, off);
                if (ov > tv || (ov == tv && oi < ti)) { tv = ov; ti = oi; }
            }
            if (lane == 0) {
                if (m == 0) { if (q > 0) knn[i * K_TOT + q - 1] = ti; }
                else        { knn[i * K_TOT + 20 + q] = ti; }
            }
            if (idx == ti) val = -DBL_MAX;  // consume winner
        }
    }
}

// ---------------------------------------------------------------------------
// Kernel 3: mutuality + sparse locality scatter + all_close.
// locality region was zeroed by hipMemsetAsync; only mutual pairs written.
// ---------------------------------------------------------------------------
__global__ __launch_bounds__(256) void finalize_k(const int* __restrict__ knn,
                                                  const float* __restrict__ adj,
                                                  const int* __restrict__ cl,
                                                  float* __restrict__ out) {
    const int gid = blockIdx.x * 256 + threadIdx.x;
    if (gid >= NN * K_TOT) return;
    const int i = gid / K_TOT;
    const int j = knn[gid];

    bool mutual = false;
#pragma unroll
    for (int s = 0; s < K_TOT; ++s) mutual |= (knn[j * K_TOT + s] == i);

    if (mutual) out[(size_t)i * NN + j] = adj[(size_t)i * NN + j];

    bool ac = mutual;
    if (!ac) {
        bool alleq = true;
#pragma unroll
        for (int m = 0; m < MM; ++m) alleq &= (cl[m * NN + i] == cl[m * NN + j]);
        ac = alleq;
    }
    out[(size_t)NN * NN + gid] = ac ? 1.0f : 0.0f;
}

// ---------------------------------------------------------------------------
extern "C" void kernel_launch(void* const* d_in, const int* in_sizes, int n_in,
                              void* d_out, int out_size, void* d_ws, size_t ws_size,
                              hipStream_t stream) {
    const float* adj = (const float*)d_in[0];
    const float* enc = (const float*)d_in[1];
    const int* batch = (const int*)d_in[2];
    const int* cl = (const int*)d_in[3];
    float* out = (float*)d_out;

    const size_t simBytes = (size_t)NN * NN * sizeof(float);   // 67.1 MB
    const size_t knnBytes = (size_t)NN * K_TOT * sizeof(int);  // 0.49 MB

    if (ws_size >= simBytes + knnBytes) {
        float* sims = (float*)d_ws;
        int* knn = (int*)((char*)d_ws + simBytes);
        hipMemsetAsync(d_out, 0, (size_t)NN * NN * sizeof(float), stream);
        gemm_f32<<<dim3(NN / 128, NN / 128), dim3(16, 16), 0, stream>>>(enc, sims);
        select_rescore<<<NN, 256, 0, stream>>>(sims, enc, batch, knn);
        finalize_k<<<(NN * K_TOT + 255) / 256, 256, 0, stream>>>(knn, adj, cl, out);
    } else {
        // fallback: stage fp32 sims in the locality region of d_out, memset after
        float* sims = out;
        int* knn = (int*)d_ws;
        gemm_f32<<<dim3(NN / 128, NN / 128), dim3(16, 16), 0, stream>>>(enc, sims);
        select_rescore<<<NN, 256, 0, stream>>>(sims, enc, batch, knn);
        hipMemsetAsync(d_out, 0, (size_t)NN * NN * sizeof(float), stream);
        finalize_k<<<(NN * K_TOT + 255) / 256, 256, 0, stream>>>(knn, adj, cl, out);
    }
}

// Round 4
// 232.327 us; speedup vs baseline: 2.4730x; 1.3491x over previous
//
#include <hip/hip_runtime.h>
#include <hip/hip_bf16.h>
#include <cfloat>

// Problem constants (fixed by the reference file)
#define NN 4096
#define DD 256
#define MM 5
#define K_TOT 30       // 20 intra + 10 inter
#define TGT_INTRA 32   // capture >= 32 intra candidates (need top-21 incl self)
#define TGT_INTER 24   // capture >= 24 inter candidates (need top-10)
#define CAND_CAP 64

typedef __attribute__((ext_vector_type(8))) short bf16x8;
typedef __attribute__((ext_vector_type(4))) float f32x4;

// ---------------------------------------------------------------------------
// Kernel 0: E fp32 -> bf16 (RNE). Selection-only precision; exact ordering
// comes from the fp64 rescore in select_rescore.
// ---------------------------------------------------------------------------
__global__ __launch_bounds__(256) void convert_bf16(const float* __restrict__ E,
                                                    ushort* __restrict__ Eb) {
    const int idx = blockIdx.x * 256 + threadIdx.x;  // one float4 per thread
    const float4 f = ((const float4*)E)[idx];
    ushort4 h;
    {
        __hip_bfloat16 a = __float2bfloat16(f.x); h.x = *(ushort*)&a;
        __hip_bfloat16 b = __float2bfloat16(f.y); h.y = *(ushort*)&b;
        __hip_bfloat16 c = __float2bfloat16(f.z); h.z = *(ushort*)&c;
        __hip_bfloat16 d = __float2bfloat16(f.w); h.w = *(ushort*)&d;
    }
    ((ushort4*)Eb)[idx] = h;
}

// ---------------------------------------------------------------------------
// Kernel 1: sim = Eb @ Eb^T via MFMA bf16, output bf16.
// 128x128 tile / block, 4 waves (2x2 of 64x64), 16x16x32 MFMA.
// LDS pitch 40 bf16 (80 B): frag-read lanes land 2-way max (free).
// Epilogue transposes C-layout through LDS -> coalesced 16 B stores.
// ---------------------------------------------------------------------------
#define BK 32
#define APITCH 40    // bf16 / row for A,B staging
#define SPITCH 136   // bf16 / row for epilogue stage

__global__ __launch_bounds__(256) void gemm_bf16(const ushort* __restrict__ Eb,
                                                 ushort* __restrict__ simb) {
    __shared__ union {
        struct { ushort A[128 * APITCH]; ushort B[128 * APITCH]; } s;  // 20 KB
        ushort stage[128 * SPITCH];                                    // 34 KB
    } lds;

    const int t = threadIdx.x;
    const int w = t >> 6, lane = t & 63;
    const int quad = lane >> 4, mr = lane & 15;
    const int rowBase = blockIdx.y * 128, colBase = blockIdx.x * 128;
    const int waveRow = (w & 1) * 64, waveCol = (w >> 1) * 64;

    f32x4 acc[4][4];
#pragma unroll
    for (int a = 0; a < 4; ++a)
#pragma unroll
        for (int b = 0; b < 4; ++b) acc[a][b] = (f32x4)(0.0f);

    for (int kc = 0; kc < DD; kc += BK) {
        // stage: 128 rows x 32 k (bf16) for A and B; 16 B chunks, 2+2 per thread
#pragma unroll
        for (int q = 0; q < 2; ++q) {
            const int cid = t * 2 + q;       // 0..511
            const int row = cid >> 2;        // 0..127
            const int ck = (cid & 3) * 8;    // bf16 offset 0,8,16,24
            const int4 va = *(const int4*)(Eb + (size_t)(rowBase + row) * DD + kc + ck);
            const int4 vb = *(const int4*)(Eb + (size_t)(colBase + row) * DD + kc + ck);
            *(int4*)(&lds.s.A[row * APITCH + ck]) = va;
            *(int4*)(&lds.s.B[row * APITCH + ck]) = vb;
        }
        __syncthreads();

        // fragments: lane holds [m=mr][k=quad*8+j] (m120-verified mapping)
        bf16x8 af[4], bfr[4];
#pragma unroll
        for (int rt = 0; rt < 4; ++rt)
            af[rt] = *(const bf16x8*)(&lds.s.A[(waveRow + rt * 16 + mr) * APITCH + quad * 8]);
#pragma unroll
        for (int ct = 0; ct < 4; ++ct)
            bfr[ct] = *(const bf16x8*)(&lds.s.B[(waveCol + ct * 16 + mr) * APITCH + quad * 8]);
#pragma unroll
        for (int rt = 0; rt < 4; ++rt)
#pragma unroll
            for (int ct = 0; ct < 4; ++ct)
                acc[rt][ct] = __builtin_amdgcn_mfma_f32_16x16x32_bf16(
                    af[rt], bfr[ct], acc[rt][ct], 0, 0, 0);
        __syncthreads();
    }

    // epilogue: C/D layout col=lane&15, row=quad*4+reg -> LDS bf16 [row][col]
#pragma unroll
    for (int rt = 0; rt < 4; ++rt)
#pragma unroll
        for (int ct = 0; ct < 4; ++ct) {
#pragma unroll
            for (int reg = 0; reg < 4; ++reg) {
                const float f = acc[rt][ct][reg];
                __hip_bfloat16 hb = __float2bfloat16(f);
                lds.stage[(waveRow + rt * 16 + quad * 4 + reg) * SPITCH +
                          waveCol + ct * 16 + mr] = *(ushort*)&hb;
            }
        }
    __syncthreads();

    // coalesced copy out: 128 rows x 256 B
#pragma unroll
    for (int it = 0; it < 8; ++it) {
        const int cid = t + it * 256;       // 0..2047
        const int row = cid >> 4;
        const int off = (cid & 15) * 8;     // bf16 elems (16 B)
        *(int4*)(simb + (size_t)(rowBase + row) * NN + colBase + off) =
            *(const int4*)(&lds.stage[row * SPITCH + off]);
    }
}

// ---------------------------------------------------------------------------
// Kernel 2 (fused): per-row candidate selection via key histogram on bf16
// sims, fp64 rescore of candidates from original fp32 E, ordered top-21/
// top-10 within single waves. Block = 256 threads = one row.
// ---------------------------------------------------------------------------
__device__ __forceinline__ unsigned f32_sortable(float f) {
    unsigned u = __float_as_uint(f);
    return (u & 0x80000000u) ? ~u : (u | 0x80000000u);  // monotone
}

__global__ __launch_bounds__(256) void select_rescore(const ushort* __restrict__ sim,
                                                      const float* __restrict__ E,
                                                      const int* __restrict__ batch,
                                                      int* __restrict__ knn) {
    __shared__ unsigned hist[2][2048];     // coarse bins = key >> 21
    __shared__ unsigned subhist[2][64];    // refine bins = (key >> 15) & 63
    __shared__ int Tc[2];
    __shared__ unsigned remc[2];
    __shared__ unsigned thrKey[2];
    __shared__ int candIdx[2][CAND_CAP];
    __shared__ double candVal[2][CAND_CAP];
    __shared__ int cnt[2];
    __shared__ float4 Ei4[DD / 4];

    const int i = blockIdx.x;
    const int t = threadIdx.x;
    const int lane = t & 63;
    const int w = t >> 6;
    const int bi = batch[i];

    // ---- init ----
#pragma unroll
    for (int s = 0; s < 16; ++s) ((unsigned*)hist)[t + s * 256] = 0u;
    if (t < 128) ((unsigned*)subhist)[t] = 0u;
    if (t < 128) ((int*)candIdx)[t] = 0x7FFFFFFF;
    if (t < 2) cnt[t] = 0;
    if (t < 2) { Tc[t] = 0; remc[t] = 1u; }
    if (t < DD / 4) Ei4[t] = ((const float4*)(E + (size_t)i * DD))[t];
    __syncthreads();

    // ---- pass 1: keys + masks + coarse histogram ----
    unsigned key[16];
    unsigned mmask = 0;  // bit u set => element u is INTER
    const ushort* simRow = sim + (size_t)i * NN;
#pragma unroll
    for (int q = 0; q < 4; ++q) {
        const int j0 = q * 1024 + t * 4;
        const ushort4 sv = *(const ushort4*)(simRow + j0);
        int bv[4];
        *(int4*)bv = *(const int4*)(batch + j0);
        const ushort se[4] = {sv.x, sv.y, sv.z, sv.w};
#pragma unroll
        for (int c = 0; c < 4; ++c) {
            const float f = __uint_as_float((unsigned)se[c] << 16);  // exact widen
            const unsigned k = f32_sortable(f);
            const int u = q * 4 + c;
            key[u] = k;
            const int m = (bv[c] == bi) ? 0 : 1;
            mmask |= (unsigned)m << u;
            atomicAdd(&hist[m][k >> 21], 1u);
        }
    }
    __syncthreads();

    // ---- pass 2: coarse threshold (wave 0 -> intra, wave 1 -> inter) ----
    if (w < 2) {
        const int m = w;
        const unsigned target = (m == 0) ? TGT_INTRA : TGT_INTER;
        const int base = (63 - lane) * 32;  // lane 0 owns the TOP chunk
        unsigned s = 0;
#pragma unroll
        for (int b = 0; b < 32; ++b) s += hist[m][base + b];
        unsigned cum = s;
        for (int off = 1; off < 64; off <<= 1) {
            const unsigned o = __shfl_up(cum, off);
            if (lane >= off) cum += o;
        }
        if (cum >= target && (cum - s) < target) {
            unsigned excl = cum - s;
            for (int b = base + 31; b >= base; --b) {
                const unsigned h = hist[m][b];
                excl += h;
                if (excl >= target) {
                    Tc[m] = b;
                    remc[m] = target - (excl - h);
                    break;
                }
            }
        }
    }
    __syncthreads();

    // ---- pass 2b: sub-histogram of the crossing bin ----
    const int T0 = Tc[0], T1 = Tc[1];
#pragma unroll
    for (int u = 0; u < 16; ++u) {
        const int m = (mmask >> u) & 1;
        const int T = m ? T1 : T0;
        if ((int)(key[u] >> 21) == T) atomicAdd(&subhist[m][(key[u] >> 15) & 63], 1u);
    }
    __syncthreads();

    // ---- pass 2c: refine threshold within the crossing bin ----
    if (w < 2) {
        const int m = w;
        const unsigned target2 = remc[m];
        const unsigned s = subhist[m][63 - lane];
        unsigned cum = s;
        for (int off = 1; off < 64; off <<= 1) {
            const unsigned o = __shfl_up(cum, off);
            if (lane >= off) cum += o;
        }
        if (cum >= target2 && (cum - s) < target2)
            thrKey[m] = ((unsigned)Tc[m] << 21) | ((unsigned)(63 - lane) << 15);
    }
    __syncthreads();

    // ---- pass 3: collect candidate indices ----
    const unsigned thr0 = thrKey[0], thr1 = thrKey[1];
#pragma unroll
    for (int q = 0; q < 4; ++q) {
#pragma unroll
        for (int c = 0; c < 4; ++c) {
            const int u = q * 4 + c;
            const int m = (mmask >> u) & 1;
            if (key[u] >= (m ? thr1 : thr0)) {
                const int pos = atomicAdd(&cnt[m], 1);
                if (pos < CAND_CAP) candIdx[m][pos] = q * 1024 + t * 4 + c;
            }
        }
    }
    __syncthreads();

    // ---- pass 4: fp64 rescore of candidates (threads 0..127) ----
    if (t < 128) {
        const int m = t >> 6;
        const int slot = t & 63;
        const int c = min(cnt[m], CAND_CAP);
        double val = -DBL_MAX;
        if (slot < c) {
            const int j = candIdx[m][slot];
            const float* ej = E + (size_t)j * DD;
            const float* ei = (const float*)Ei4;
            double a0 = 0, a1 = 0, a2 = 0, a3 = 0;
#pragma unroll 8
            for (int k = 0; k < DD; k += 4) {
                const float4 e = *(const float4*)(ej + k);
                a0 = fma((double)ei[k + 0], (double)e.x, a0);
                a1 = fma((double)ei[k + 1], (double)e.y, a1);
                a2 = fma((double)ei[k + 2], (double)e.z, a2);
                a3 = fma((double)ei[k + 3], (double)e.w, a3);
            }
            val = (a0 + a1) + (a2 + a3);
        }
        candVal[m][slot] = val;
    }
    __syncthreads();

    // ---- pass 5: ordered selection, wave 0 = intra(21, drop rank0),
    //              wave 1 = inter(10) ----
    if (w < 2) {
        const int m = w;
        double val = candVal[m][lane];
        int idx = candIdx[m][lane];
        const int rounds = (m == 0) ? 21 : 10;
        for (int q = 0; q < rounds; ++q) {
            double tv = val;
            int ti = idx;
#pragma unroll
            for (int off = 32; off; off >>= 1) {
                const double ov = __shfl_xor(tv, off);
                const int oi = __shfl_xor(ti, off);
                if (ov > tv || (ov == tv && oi < ti)) { tv = ov; ti = oi; }
            }
            if (lane == 0) {
                if (m == 0) { if (q > 0) knn[i * K_TOT + q - 1] = ti; }
                else        { knn[i * K_TOT + 20 + q] = ti; }
            }
            if (idx == ti) val = -DBL_MAX;
        }
    }
}

// ---------------------------------------------------------------------------
// Kernel 3: mutuality + sparse locality scatter + all_close.
// ---------------------------------------------------------------------------
__global__ __launch_bounds__(256) void finalize_k(const int* __restrict__ knn,
                                                  const float* __restrict__ adj,
                                                  const int* __restrict__ cl,
                                                  float* __restrict__ out) {
    const int gid = blockIdx.x * 256 + threadIdx.x;
    if (gid >= NN * K_TOT) return;
    const int i = gid / K_TOT;
    const int j = knn[gid];

    bool mutual = false;
#pragma unroll
    for (int s = 0; s < K_TOT; ++s) mutual |= (knn[j * K_TOT + s] == i);

    if (mutual) out[(size_t)i * NN + j] = adj[(size_t)i * NN + j];

    bool ac = mutual;
    if (!ac) {
        bool alleq = true;
#pragma unroll
        for (int m = 0; m < MM; ++m) alleq &= (cl[m * NN + i] == cl[m * NN + j]);
        ac = alleq;
    }
    out[(size_t)NN * NN + gid] = ac ? 1.0f : 0.0f;
}

// ---------------------------------------------------------------------------
extern "C" void kernel_launch(void* const* d_in, const int* in_sizes, int n_in,
                              void* d_out, int out_size, void* d_ws, size_t ws_size,
                              hipStream_t stream) {
    const float* adj = (const float*)d_in[0];
    const float* enc = (const float*)d_in[1];
    const int* batch = (const int*)d_in[2];
    const int* cl = (const int*)d_in[3];
    float* out = (float*)d_out;

    const size_t simB = (size_t)NN * NN * sizeof(ushort);   // 33.6 MB
    const size_t ebB = (size_t)NN * DD * sizeof(ushort);    // 2.1 MB
    const size_t knnB = (size_t)NN * K_TOT * sizeof(int);   // 0.49 MB

    const dim3 gGrid(NN / 128, NN / 128);

    if (ws_size >= simB + ebB + knnB) {
        ushort* simb = (ushort*)d_ws;
        ushort* Eb = (ushort*)((char*)d_ws + simB);
        int* knn = (int*)((char*)d_ws + simB + ebB);
        hipMemsetAsync(d_out, 0, (size_t)NN * NN * sizeof(float), stream);
        convert_bf16<<<NN * DD / 4 / 256, 256, 0, stream>>>(enc, Eb);
        gemm_bf16<<<gGrid, 256, 0, stream>>>(Eb, simb);
        select_rescore<<<NN, 256, 0, stream>>>(simb, enc, batch, knn);
        finalize_k<<<(NN * K_TOT + 255) / 256, 256, 0, stream>>>(knn, adj, cl, out);
    } else {
        // fallback: stage bf16 sims in the locality region of d_out, memset after
        ushort* simb = (ushort*)d_out;
        ushort* Eb = (ushort*)d_ws;
        int* knn = (int*)((char*)d_ws + ebB);
        convert_bf16<<<NN * DD / 4 / 256, 256, 0, stream>>>(enc, Eb);
        gemm_bf16<<<gGrid, 256, 0, stream>>>(Eb, simb);
        select_rescore<<<NN, 256, 0, stream>>>(simb, enc, batch, knn);
        hipMemsetAsync(d_out, 0, (size_t)NN * NN * sizeof(float), stream);
        finalize_k<<<(NN * K_TOT + 255) / 256, 256, 0, stream>>>(knn, adj, cl, out);
    }
}

// Round 6
// 227.184 us; speedup vs baseline: 2.5290x; 1.0226x over previous
//
#include <hip/hip_runtime.h>
#include <hip/hip_bf16.h>
#include <cfloat>

// Problem constants (fixed by the reference file)
#define NN 4096
#define DD 256
#define MM 5
#define K_TOT 30       // 20 intra + 10 inter
#define TGT_INTRA 32   // capture >= 32 intra candidates (need top-21 incl self)
#define TGT_INTER 24   // capture >= 24 inter candidates (need top-10)
#define CAND_CAP 64

typedef __attribute__((ext_vector_type(8))) short bf16x8;
typedef __attribute__((ext_vector_type(4))) float f32x4;

// async global->LDS, 16 B per lane; LDS dest = wave-uniform base + lane*16
__device__ __forceinline__ void async16(const void* g, void* l) {
    __builtin_amdgcn_global_load_lds((__attribute__((address_space(1))) void*)g,
                                     (__attribute__((address_space(3))) void*)l,
                                     16, 0, 0);
}

// ---------------------------------------------------------------------------
// Kernel 0: E fp32 -> bf16 (RNE). Selection-only precision; exact ordering
// comes from the fp64 rescore in select_rescore.
// ---------------------------------------------------------------------------
__global__ __launch_bounds__(256) void convert_bf16(const float* __restrict__ E,
                                                    ushort* __restrict__ Eb) {
    const int idx = blockIdx.x * 256 + threadIdx.x;
    const float4 f = ((const float4*)E)[idx];
    ushort4 h;
    {
        __hip_bfloat16 a = __float2bfloat16(f.x); h.x = *(ushort*)&a;
        __hip_bfloat16 b = __float2bfloat16(f.y); h.y = *(ushort*)&b;
        __hip_bfloat16 c = __float2bfloat16(f.z); h.z = *(ushort*)&c;
        __hip_bfloat16 d = __float2bfloat16(f.w); h.w = *(ushort*)&d;
    }
    ((ushort4*)Eb)[idx] = h;
}

// ---------------------------------------------------------------------------
// Kernel 1: sim = Eb @ Eb^T via MFMA bf16 -> bf16 out. 128x128 tile, 4 waves
// (2x2 of 64x64), 16x16x32 MFMA, BK=32 (8 K-iters). Staging via
// global_load_lds width=16 into unpadded [128][32] bf16 with XOR chunk
// swizzle: LDS slot c of row r holds global chunk c ^ ((r>>1)&3) -> fragment
// reads are 2-way max (free), staging satisfies the wave-uniform-base rule.
// ---------------------------------------------------------------------------
__global__ __launch_bounds__(256) void gemm_bf16(const ushort* __restrict__ Eb,
                                                 ushort* __restrict__ simb) {
    __shared__ union {
        struct { ushort A[128 * 32]; ushort B[128 * 32]; } s;  // 8 KB + 8 KB
        ushort stage[128 * 136];                               // 34 KB epilogue
    } lds;

    const int t = threadIdx.x;
    const int w = t >> 6, lane = t & 63;
    const int quad = lane >> 4, mr = lane & 15;
    const int rowBase = blockIdx.y * 128, colBase = blockIdx.x * 128;
    const int waveRow = (w & 1) * 64, waveCol = (w >> 1) * 64;

    const int lrow = lane >> 2;              // 0..15 row within 16-row slab
    const int lslot = lane & 3;              // LDS chunk slot
    const int gchunk = lslot ^ ((lrow >> 1) & 3);  // swizzled global chunk

    f32x4 acc[4][4];
#pragma unroll
    for (int a = 0; a < 4; ++a)
#pragma unroll
        for (int b = 0; b < 4; ++b) acc[a][b] = (f32x4)(0.0f);

    for (int kc = 0; kc < DD; kc += 32) {
        // wave w stages A rows [w*32, w*32+32) and same B rows: 2 slabs each
#pragma unroll
        for (int n = 0; n < 2; ++n) {
            const int r = w * 32 + n * 16 + lrow;  // (r>>1)&3 == (lrow>>1)&3
            const ushort* ga = Eb + (size_t)(rowBase + r) * DD + kc + gchunk * 8;
            const ushort* gb = Eb + (size_t)(colBase + r) * DD + kc + gchunk * 8;
            async16(ga, &lds.s.A[(w * 32 + n * 16) * 32]);
            async16(gb, &lds.s.B[(w * 32 + n * 16) * 32]);
        }
        __syncthreads();  // drains vmcnt before barrier (compiler-enforced)

        const int swzF = (mr >> 1) & 3;
        bf16x8 af[4], bfr[4];
#pragma unroll
        for (int rt = 0; rt < 4; ++rt)
            af[rt] = *(const bf16x8*)&lds.s.A[(waveRow + rt * 16 + mr) * 32 +
                                              ((quad ^ swzF) * 8)];
#pragma unroll
        for (int ct = 0; ct < 4; ++ct)
            bfr[ct] = *(const bf16x8*)&lds.s.B[(waveCol + ct * 16 + mr) * 32 +
                                               ((quad ^ swzF) * 8)];
#pragma unroll
        for (int rt = 0; rt < 4; ++rt)
#pragma unroll
            for (int ct = 0; ct < 4; ++ct)
                acc[rt][ct] = __builtin_amdgcn_mfma_f32_16x16x32_bf16(
                    af[rt], bfr[ct], acc[rt][ct], 0, 0, 0);
        __syncthreads();
    }

    // epilogue: C/D layout (col=mr, row=quad*4+reg) -> LDS bf16 -> coalesced
#pragma unroll
    for (int rt = 0; rt < 4; ++rt)
#pragma unroll
        for (int ct = 0; ct < 4; ++ct)
#pragma unroll
            for (int reg = 0; reg < 4; ++reg) {
                __hip_bfloat16 hb = __float2bfloat16(acc[rt][ct][reg]);
                lds.stage[(waveRow + rt * 16 + quad * 4 + reg) * 136 +
                          waveCol + ct * 16 + mr] = *(ushort*)&hb;
            }
    __syncthreads();
#pragma unroll
    for (int it = 0; it < 8; ++it) {
        const int cid = t + it * 256;
        const int row = cid >> 4;
        const int off = (cid & 15) * 8;
        *(int4*)(simb + (size_t)(rowBase + row) * NN + colBase + off) =
            *(const int4*)&lds.stage[row * 136 + off];
    }
}

// ---------------------------------------------------------------------------
// Kernel 2 (fused): two-level packed histogram over 16-bit bf16 sortable
// keys (coarse = key>>8 [sign+7 exp bits -> EXPONENTIAL bins, must refine],
// sub = key&0xFF of each mask's crossing bin) -> exact 16-bit key threshold.
// Overshoot = bf16 tie multiplicity (~1-2) so CAND_CAP=64 is safe. Both
// masks packed in one u32 (intra lo16 / inter hi16). fp64 rescore from fp32
// E, ordered top-21/top-10 in single waves. Block = 256 threads = one row.
// ---------------------------------------------------------------------------
__global__ __launch_bounds__(256) void select_rescore(const ushort* __restrict__ sim,
                                                      const float* __restrict__ E,
                                                      const int* __restrict__ batch,
                                                      int* __restrict__ knn) {
    __shared__ unsigned hist[256];     // coarse, packed
    __shared__ unsigned subhist[256];  // refine, packed
    __shared__ unsigned wsum[4];
    __shared__ int cb[2];              // coarse crossing bin per mask
    __shared__ unsigned remc[2];       // remaining count inside crossing bin
    __shared__ unsigned thrKey[2];     // exact 16-bit key threshold
    __shared__ int candIdx[2][CAND_CAP];
    __shared__ double candVal[2][CAND_CAP];
    __shared__ int cnt[2];
    __shared__ float4 Ei4[DD / 4];

    const int i = blockIdx.x;
    const int t = threadIdx.x;
    const int lane = t & 63;
    const int w = t >> 6;
    const int bi = batch[i];

    hist[t] = 0u;
    subhist[t] = 0u;
    if (t < 128) ((int*)candIdx)[t] = 0x7FFFFFFF;
    if (t < 2) { cnt[t] = 0; cb[t] = 0; remc[t] = 1u; thrKey[t] = 0u; }
    if (t < DD / 4) Ei4[t] = ((const float4*)(E + (size_t)i * DD))[t];
    __syncthreads();

    // ---- pass 1: keys + masks + packed coarse histogram (j = t*16 + c) ----
    unsigned short key[16];
    unsigned mmask = 0;  // bit c set => INTER
    {
        const ushort* sp = sim + (size_t)i * NN + t * 16;
        const int4 s0 = *(const int4*)sp;
        const int4 s1 = *(const int4*)(sp + 8);
        const unsigned sw[8] = {(unsigned)s0.x, (unsigned)s0.y, (unsigned)s0.z,
                                (unsigned)s0.w, (unsigned)s1.x, (unsigned)s1.y,
                                (unsigned)s1.z, (unsigned)s1.w};
        const int* bp = batch + t * 16;
        int bv[16];
        *(int4*)&bv[0] = *(const int4*)bp;
        *(int4*)&bv[4] = *(const int4*)(bp + 4);
        *(int4*)&bv[8] = *(const int4*)(bp + 8);
        *(int4*)&bv[12] = *(const int4*)(bp + 12);
#pragma unroll
        for (int c = 0; c < 16; ++c) {
            const unsigned u = (sw[c >> 1] >> ((c & 1) * 16)) & 0xFFFFu;
            const unsigned k = (u & 0x8000u) ? (u ^ 0xFFFFu) : (u | 0x8000u);
            key[c] = (unsigned short)k;
            const int m = (bv[c] == bi) ? 0 : 1;
            mmask |= (unsigned)m << c;
            atomicAdd(&hist[k >> 8], m ? 0x10000u : 1u);
        }
    }
    __syncthreads();

    // ---- pass 2: packed descending scan over coarse bins ----
    {
        const int b = 255 - t;  // thread t owns bin b (t ascending = descending key)
        const unsigned h = hist[b];
        unsigned cum = h;
        for (int off = 1; off < 64; off <<= 1) {
            const unsigned o = __shfl_up(cum, off);
            if (lane >= off) cum += o;
        }
        if (lane == 63) wsum[w] = cum;
        __syncthreads();
        unsigned add = 0;
        for (int ww = 0; ww < w; ++ww) add += wsum[ww];
        cum += add;
        const unsigned cI = cum & 0xFFFFu, hI = h & 0xFFFFu;
        const unsigned cT = cum >> 16, hT = h >> 16;
        if (cI >= TGT_INTRA && cI - hI < TGT_INTRA) {
            cb[0] = b;
            remc[0] = TGT_INTRA - (cI - hI);  // >= 1, to find inside this bin
        }
        if (cT >= TGT_INTER && cT - hT < TGT_INTER) {
            cb[1] = b;
            remc[1] = TGT_INTER - (cT - hT);
        }
    }
    __syncthreads();

    // ---- pass 2b: packed sub-histogram of each mask's crossing bin ----
    {
        const int cb0 = cb[0], cb1 = cb[1];
#pragma unroll
        for (int c = 0; c < 16; ++c) {
            const int m = (mmask >> c) & 1;
            if ((int)(key[c] >> 8) == (m ? cb1 : cb0))
                atomicAdd(&subhist[key[c] & 0xFF], m ? 0x10000u : 1u);
        }
    }
    __syncthreads();

    // ---- pass 2c: packed descending scan over sub-bins -> exact threshold ----
    {
        const unsigned rI = remc[0], rT = remc[1];
        const int cb0 = cb[0], cb1 = cb[1];
        const int b = 255 - t;
        const unsigned h = subhist[b];
        unsigned cum = h;
        for (int off = 1; off < 64; off <<= 1) {
            const unsigned o = __shfl_up(cum, off);
            if (lane >= off) cum += o;
        }
        if (lane == 63) wsum[w] = cum;
        __syncthreads();
        unsigned add = 0;
        for (int ww = 0; ww < w; ++ww) add += wsum[ww];
        cum += add;
        const unsigned cI = cum & 0xFFFFu, hI = h & 0xFFFFu;
        const unsigned cT = cum >> 16, hT = h >> 16;
        if (cI >= rI && cI - hI < rI) thrKey[0] = ((unsigned)cb0 << 8) | (unsigned)b;
        if (cT >= rT && cT - hT < rT) thrKey[1] = ((unsigned)cb1 << 8) | (unsigned)b;
    }
    __syncthreads();

    // ---- pass 3: collect candidates (>= exact threshold; ties included) ----
    {
        const unsigned thr0 = thrKey[0], thr1 = thrKey[1];
#pragma unroll
        for (int c = 0; c < 16; ++c) {
            const int m = (mmask >> c) & 1;
            if ((unsigned)key[c] >= (m ? thr1 : thr0)) {
                const int pos = atomicAdd(&cnt[m], 1);
                if (pos < CAND_CAP) candIdx[m][pos] = t * 16 + c;
            }
        }
    }
    __syncthreads();

    // ---- pass 4: fp64 rescore of candidates (threads 0..127) ----
    if (t < 128) {
        const int m = t >> 6;
        const int slot = t & 63;
        const int c = min(cnt[m], CAND_CAP);
        double val = -DBL_MAX;
        if (slot < c) {
            const int j = candIdx[m][slot];
            const float* ej = E + (size_t)j * DD;
            const float* ei = (const float*)Ei4;
            double a0 = 0, a1 = 0, a2 = 0, a3 = 0;
#pragma unroll 8
            for (int k = 0; k < DD; k += 4) {
                const float4 e = *(const float4*)(ej + k);
                a0 = fma((double)ei[k + 0], (double)e.x, a0);
                a1 = fma((double)ei[k + 1], (double)e.y, a1);
                a2 = fma((double)ei[k + 2], (double)e.z, a2);
                a3 = fma((double)ei[k + 3], (double)e.w, a3);
            }
            val = (a0 + a1) + (a2 + a3);
        }
        candVal[m][slot] = val;
    }
    __syncthreads();

    // ---- pass 5: ordered selection, wave 0 = intra(21, drop rank0),
    //              wave 1 = inter(10) ----
    if (w < 2) {
        const int m = w;
        double val = candVal[m][lane];
        int idx = candIdx[m][lane];
        const int rounds = (m == 0) ? 21 : 10;
        for (int q = 0; q < rounds; ++q) {
            double tv = val;
            int ti = idx;
#pragma unroll
            for (int off = 32; off; off >>= 1) {
                const double ov = __shfl_xor(tv, off);
                const int oi = __shfl_xor(ti, off);
                if (ov > tv || (ov == tv && oi < ti)) { tv = ov; ti = oi; }
            }
            if (lane == 0) {
                if (m == 0) { if (q > 0) knn[i * K_TOT + q - 1] = ti; }
                else        { knn[i * K_TOT + 20 + q] = ti; }
            }
            if (idx == ti) val = -DBL_MAX;
        }
    }
}

// ---------------------------------------------------------------------------
// Kernel 3: mutuality + sparse locality scatter + all_close.
// ---------------------------------------------------------------------------
__global__ __launch_bounds__(256) void finalize_k(const int* __restrict__ knn,
                                                  const float* __restrict__ adj,
                                                  const int* __restrict__ cl,
                                                  float* __restrict__ out) {
    const int gid = blockIdx.x * 256 + threadIdx.x;
    if (gid >= NN * K_TOT) return;
    const int i = gid / K_TOT;
    const int j = knn[gid];

    bool mutual = false;
#pragma unroll
    for (int s = 0; s < K_TOT; ++s) mutual |= (knn[j * K_TOT + s] == i);

    if (mutual) out[(size_t)i * NN + j] = adj[(size_t)i * NN + j];

    bool ac = mutual;
    if (!ac) {
        bool alleq = true;
#pragma unroll
        for (int m = 0; m < MM; ++m) alleq &= (cl[m * NN + i] == cl[m * NN + j]);
        ac = alleq;
    }
    out[(size_t)NN * NN + gid] = ac ? 1.0f : 0.0f;
}

// ---------------------------------------------------------------------------
extern "C" void kernel_launch(void* const* d_in, const int* in_sizes, int n_in,
                              void* d_out, int out_size, void* d_ws, size_t ws_size,
                              hipStream_t stream) {
    const float* adj = (const float*)d_in[0];
    const float* enc = (const float*)d_in[1];
    const int* batch = (const int*)d_in[2];
    const int* cl = (const int*)d_in[3];
    float* out = (float*)d_out;

    const size_t simB = (size_t)NN * NN * sizeof(ushort);   // 33.6 MB
    const size_t ebB = (size_t)NN * DD * sizeof(ushort);    // 2.1 MB
    const size_t knnB = (size_t)NN * K_TOT * sizeof(int);   // 0.49 MB

    const dim3 gGrid(NN / 128, NN / 128);

    if (ws_size >= simB + ebB + knnB) {
        ushort* simb = (ushort*)d_ws;
        ushort* Eb = (ushort*)((char*)d_ws + simB);
        int* knn = (int*)((char*)d_ws + simB + ebB);
        hipMemsetAsync(d_out, 0, (size_t)NN * NN * sizeof(float), stream);
        convert_bf16<<<NN * DD / 4 / 256, 256, 0, stream>>>(enc, Eb);
        gemm_bf16<<<gGrid, 256, 0, stream>>>(Eb, simb);
        select_rescore<<<NN, 256, 0, stream>>>(simb, enc, batch, knn);
        finalize_k<<<(NN * K_TOT + 255) / 256, 256, 0, stream>>>(knn, adj, cl, out);
    } else {
        // fallback: stage bf16 sims in the locality region of d_out, memset after
        ushort* simb = (ushort*)d_out;
        ushort* Eb = (ushort*)d_ws;
        int* knn = (int*)((char*)d_ws + ebB);
        convert_bf16<<<NN * DD / 4 / 256, 256, 0, stream>>>(enc, Eb);
        gemm_bf16<<<gGrid, 256, 0, stream>>>(Eb, simb);
        select_rescore<<<NN, 256, 0, stream>>>(simb, enc, batch, knn);
        hipMemsetAsync(d_out, 0, (size_t)NN * NN * sizeof(float), stream);
        finalize_k<<<(NN * K_TOT + 255) / 256, 256, 0, stream>>>(knn, adj, cl, out);
    }
}

// Round 7
// 212.900 us; speedup vs baseline: 2.6987x; 1.0671x over previous
//
#include <hip/hip_runtime.h>
#include <hip/hip_bf16.h>
#include <cfloat>

// Problem constants (fixed by the reference file)
#define NN 4096
#define DD 256
#define MM 5
#define K_TOT 30       // 20 intra + 10 inter
#define TGT_INTRA 32   // capture >= 32 intra candidates (need top-21 incl self)
#define TGT_INTER 24   // capture >= 24 inter candidates (need top-10)
#define CAND_CAP 64

typedef __attribute__((ext_vector_type(8))) short bf16x8;
typedef __attribute__((ext_vector_type(4))) float f32x4;

// async global->LDS, 16 B per lane; LDS dest = wave-uniform base + lane*16
__device__ __forceinline__ void async16(const void* g, void* l) {
    __builtin_amdgcn_global_load_lds((__attribute__((address_space(1))) void*)g,
                                     (__attribute__((address_space(3))) void*)l,
                                     16, 0, 0);
}

// ---------------------------------------------------------------------------
// Kernel 0: E fp32 -> bf16 (RNE). Selection-only precision; exact ordering
// comes from the fp64 rescore in select_rescore.
// ---------------------------------------------------------------------------
__global__ __launch_bounds__(256) void convert_bf16(const float* __restrict__ E,
                                                    ushort* __restrict__ Eb) {
    const int idx = blockIdx.x * 256 + threadIdx.x;
    const float4 f = ((const float4*)E)[idx];
    ushort4 h;
    {
        __hip_bfloat16 a = __float2bfloat16(f.x); h.x = *(ushort*)&a;
        __hip_bfloat16 b = __float2bfloat16(f.y); h.y = *(ushort*)&b;
        __hip_bfloat16 c = __float2bfloat16(f.z); h.z = *(ushort*)&c;
        __hip_bfloat16 d = __float2bfloat16(f.w); h.w = *(ushort*)&d;
    }
    ((ushort4*)Eb)[idx] = h;
}

// ---------------------------------------------------------------------------
// Kernel 1: sim = Eb @ Eb^T via MFMA bf16 -> bf16 out. 128x128 tile, 4 waves
// (2x2 of 64x64), 16x16x32 MFMA, BK=32. global_load_lds width=16 staging
// into unpadded [128][32] with XOR chunk swizzle (2-way max = free).
// Epilogue now staged in 4 chunks of 32 rows through the 16 KB A/B buffers:
// LDS_Block_Size 34->16.4 KB doubles resident blocks for the latency-bound
// K-loop.
// ---------------------------------------------------------------------------
__global__ __launch_bounds__(256) void gemm_bf16(const ushort* __restrict__ Eb,
                                                 ushort* __restrict__ simb) {
    __shared__ union {
        struct { ushort A[128 * 32]; ushort B[128 * 32]; } s;  // 8 KB + 8 KB
        ushort stage[32 * 136];                                // 8.7 KB epilogue
    } lds;

    const int t = threadIdx.x;
    const int w = t >> 6, lane = t & 63;
    const int quad = lane >> 4, mr = lane & 15;
    const int rowBase = blockIdx.y * 128, colBase = blockIdx.x * 128;
    const int waveRow = (w & 1) * 64, waveCol = (w >> 1) * 64;

    const int lrow = lane >> 2;              // 0..15 row within 16-row slab
    const int lslot = lane & 3;              // LDS chunk slot
    const int gchunk = lslot ^ ((lrow >> 1) & 3);  // swizzled global chunk

    f32x4 acc[4][4];
#pragma unroll
    for (int a = 0; a < 4; ++a)
#pragma unroll
        for (int b = 0; b < 4; ++b) acc[a][b] = (f32x4)(0.0f);

    for (int kc = 0; kc < DD; kc += 32) {
#pragma unroll
        for (int n = 0; n < 2; ++n) {
            const int r = w * 32 + n * 16 + lrow;  // (r>>1)&3 == (lrow>>1)&3
            const ushort* ga = Eb + (size_t)(rowBase + r) * DD + kc + gchunk * 8;
            const ushort* gb = Eb + (size_t)(colBase + r) * DD + kc + gchunk * 8;
            async16(ga, &lds.s.A[(w * 32 + n * 16) * 32]);
            async16(gb, &lds.s.B[(w * 32 + n * 16) * 32]);
        }
        __syncthreads();

        const int swzF = (mr >> 1) & 3;
        bf16x8 af[4], bfr[4];
#pragma unroll
        for (int rt = 0; rt < 4; ++rt)
            af[rt] = *(const bf16x8*)&lds.s.A[(waveRow + rt * 16 + mr) * 32 +
                                              ((quad ^ swzF) * 8)];
#pragma unroll
        for (int ct = 0; ct < 4; ++ct)
            bfr[ct] = *(const bf16x8*)&lds.s.B[(waveCol + ct * 16 + mr) * 32 +
                                               ((quad ^ swzF) * 8)];
#pragma unroll
        for (int rt = 0; rt < 4; ++rt)
#pragma unroll
            for (int ct = 0; ct < 4; ++ct)
                acc[rt][ct] = __builtin_amdgcn_mfma_f32_16x16x32_bf16(
                    af[rt], bfr[ct], acc[rt][ct], 0, 0, 0);
        __syncthreads();
    }

    // epilogue: 4 chunks of 32 tile-rows through the 8.7 KB stage buffer
#pragma unroll
    for (int c = 0; c < 4; ++c) {
        __syncthreads();  // stage free (K-loop done / prev copy done)
        if ((w & 1) == (c >> 1)) {
            const int rtBase = 2 * (c & 1);
#pragma unroll
            for (int r2 = 0; r2 < 2; ++r2) {
                const int rt = rtBase + r2;
#pragma unroll
                for (int ct = 0; ct < 4; ++ct)
#pragma unroll
                    for (int reg = 0; reg < 4; ++reg) {
                        __hip_bfloat16 hb = __float2bfloat16(acc[rt][ct][reg]);
                        const int lr2 = r2 * 16 + quad * 4 + reg;  // 0..31
                        lds.stage[lr2 * 136 + waveCol + ct * 16 + mr] = *(ushort*)&hb;
                    }
            }
        }
        __syncthreads();
#pragma unroll
        for (int it = 0; it < 2; ++it) {
            const int cid = t + it * 256;   // 0..511 (32 rows x 16 int4)
            const int row = cid >> 4;
            const int off = (cid & 15) * 8;
            *(int4*)(simb + (size_t)(rowBase + c * 32 + row) * NN + colBase + off) =
                *(const int4*)&lds.stage[row * 136 + off];
        }
    }
}

// ---------------------------------------------------------------------------
// Kernel 2: ONE WAVE PER ROW (4 rows/block, symmetric work, no idle waves).
// Per wave: 64 keys/lane in registers (packed u16x2), wave-private two-level
// packed histogram (intra lo16 / inter hi16) -> exact 16-bit bf16-key
// threshold, candidate collect, fp64 rescore (E[i] wave-uniform -> scalar
// loads), rank-based ordered output (replaces 31 iterative argmax rounds).
// ---------------------------------------------------------------------------
__global__ __launch_bounds__(256) void select_rescore(const ushort* __restrict__ sim,
                                                      const float* __restrict__ E,
                                                      const int* __restrict__ batch,
                                                      int* __restrict__ knn) {
    __shared__ unsigned histS[4][256];
    __shared__ unsigned subS[4][256];
    __shared__ int candIdxS[4][2][CAND_CAP];
    __shared__ double candValS[4][2][CAND_CAP];
    __shared__ int cntS[4][2];
    __shared__ int cbS[4][2];
    __shared__ unsigned remS[4][2];
    __shared__ unsigned thrS[4][2];

    const int t = threadIdx.x;
    const int w = t >> 6, lane = t & 63;
    const int i = __builtin_amdgcn_readfirstlane(blockIdx.x * 4 + w);
    const int bi = batch[i];

    unsigned* hist = histS[w];
    unsigned* sub = subS[w];

#pragma unroll
    for (int b = 0; b < 4; ++b) { hist[lane * 4 + b] = 0u; sub[lane * 4 + b] = 0u; }
    if (lane < 2) cntS[w][lane] = 0;
    __syncthreads();

    // ---- pass 1: load 64 elems/lane, build keys + inter-mask + histogram ----
    // element j = c*512 + lane*8 + e  (16 B / lane per chunk: fully coalesced)
    unsigned kp[32];                 // packed sortable keys (2 per u32)
    unsigned long long interm = 0;   // bit (c*8+e) => batch differs
    {
        const ushort* sp = sim + (size_t)i * NN + lane * 8;
        const int* bp = batch + lane * 8;
#pragma unroll
        for (int c = 0; c < 8; ++c) {
            const int4 sv = *(const int4*)(sp + c * 512);
            int bb[8];
            *(int4*)&bb[0] = *(const int4*)(bp + c * 512);
            *(int4*)&bb[4] = *(const int4*)(bp + c * 512 + 4);
            const unsigned uu[4] = {(unsigned)sv.x, (unsigned)sv.y,
                                    (unsigned)sv.z, (unsigned)sv.w};
#pragma unroll
            for (int p = 0; p < 4; ++p) {
                const unsigned u = uu[p];
                const unsigned sgn = u & 0x80008000u;
                // per-half monotone transform: pos: ^0x8000, neg: ^0xFFFF
                const unsigned k2 = u ^ (0x80008000u | ((sgn >> 15) * 0x7FFFu));
                kp[c * 4 + p] = k2;
                const int e0 = 2 * p, e1 = 2 * p + 1;
                const unsigned m0 = (bb[e0] == bi) ? 0u : 1u;
                const unsigned m1 = (bb[e1] == bi) ? 0u : 1u;
                interm |= (unsigned long long)m0 << (c * 8 + e0);
                interm |= (unsigned long long)m1 << (c * 8 + e1);
                atomicAdd(&hist[(k2 >> 8) & 0xFF], m0 ? 0x10000u : 1u);
                atomicAdd(&hist[k2 >> 24], m1 ? 0x10000u : 1u);
            }
        }
    }
    __syncthreads();

    // ---- pass 2: wave-local packed descending scan over coarse bins ----
    {
        const unsigned* hb = &hist[lane * 4];
        const unsigned s4 = hb[0] + hb[1] + hb[2] + hb[3];
        unsigned suf = s4;  // suffix-inclusive over lanes >= lane (higher bins)
#pragma unroll
        for (int off = 1; off < 64; off <<= 1) {
            const unsigned o = __shfl_down(suf, off);
            if (lane + off < 64) suf += o;
        }
        unsigned cum = suf - s4;  // count in bins above this lane's range
#pragma unroll
        for (int b = 3; b >= 0; --b) {
            const unsigned h = hb[b];
            const unsigned prev = cum;
            cum += h;
            if ((cum & 0xFFFFu) >= TGT_INTRA && (prev & 0xFFFFu) < TGT_INTRA) {
                cbS[w][0] = lane * 4 + b;
                remS[w][0] = TGT_INTRA - (prev & 0xFFFFu);
            }
            if ((cum >> 16) >= TGT_INTER && (prev >> 16) < TGT_INTER) {
                cbS[w][1] = lane * 4 + b;
                remS[w][1] = TGT_INTER - (prev >> 16);
            }
        }
    }
    __syncthreads();

    // ---- pass 2b: sub-histogram of crossing bins (low byte) ----
    {
        const int cb0 = cbS[w][0], cb1 = cbS[w][1];
#pragma unroll
        for (int c = 0; c < 8; ++c)
#pragma unroll
            for (int p = 0; p < 4; ++p) {
                const unsigned k2 = kp[c * 4 + p];
                const unsigned k0 = k2 & 0xFFFFu, k1 = k2 >> 16;
                const int m0 = (interm >> (c * 8 + 2 * p)) & 1;
                const int m1 = (interm >> (c * 8 + 2 * p + 1)) & 1;
                if ((int)(k0 >> 8) == (m0 ? cb1 : cb0))
                    atomicAdd(&sub[k0 & 0xFF], m0 ? 0x10000u : 1u);
                if ((int)(k1 >> 8) == (m1 ? cb1 : cb0))
                    atomicAdd(&sub[k1 & 0xFF], m1 ? 0x10000u : 1u);
            }
    }
    __syncthreads();

    // ---- pass 2c: scan sub-bins -> exact 16-bit thresholds ----
    {
        const unsigned rI = remS[w][0], rT = remS[w][1];
        const int cb0 = cbS[w][0], cb1 = cbS[w][1];
        const unsigned* sb = &sub[lane * 4];
        const unsigned s4 = sb[0] + sb[1] + sb[2] + sb[3];
        unsigned suf = s4;
#pragma unroll
        for (int off = 1; off < 64; off <<= 1) {
            const unsigned o = __shfl_down(suf, off);
            if (lane + off < 64) suf += o;
        }
        unsigned cum = suf - s4;
#pragma unroll
        for (int b = 3; b >= 0; --b) {
            const unsigned h = sb[b];
            const unsigned prev = cum;
            cum += h;
            if ((cum & 0xFFFFu) >= rI && (prev & 0xFFFFu) < rI)
                thrS[w][0] = ((unsigned)cb0 << 8) | (unsigned)(lane * 4 + b);
            if ((cum >> 16) >= rT && (prev >> 16) < rT)
                thrS[w][1] = ((unsigned)cb1 << 8) | (unsigned)(lane * 4 + b);
        }
    }
    __syncthreads();

    // ---- pass 3: collect candidate indices ----
    {
        const unsigned thr0 = thrS[w][0], thr1 = thrS[w][1];
#pragma unroll
        for (int c = 0; c < 8; ++c)
#pragma unroll
            for (int p = 0; p < 4; ++p) {
                const unsigned k2 = kp[c * 4 + p];
                const unsigned k0 = k2 & 0xFFFFu, k1 = k2 >> 16;
                const int m0 = (interm >> (c * 8 + 2 * p)) & 1;
                const int m1 = (interm >> (c * 8 + 2 * p + 1)) & 1;
                if (k0 >= (m0 ? thr1 : thr0)) {
                    const int pos = atomicAdd(&cntS[w][m0], 1);
                    if (pos < CAND_CAP) candIdxS[w][m0][pos] = c * 512 + lane * 8 + 2 * p;
                }
                if (k1 >= (m1 ? thr1 : thr0)) {
                    const int pos = atomicAdd(&cntS[w][m1], 1);
                    if (pos < CAND_CAP) candIdxS[w][m1][pos] = c * 512 + lane * 8 + 2 * p + 1;
                }
            }
    }
    __syncthreads();

    // ---- pass 4: fp64 rescore; E[i] is wave-uniform -> scalar loads ----
    const int c0 = min(cntS[w][0], CAND_CAP);
    const int c1 = min(cntS[w][1], CAND_CAP);
    {
        const int tot = c0 + c1;
        const float* ei = E + (size_t)i * DD;
        for (int base = 0; base < tot; base += 64) {
            const int slot = base + lane;
            if (slot < tot) {
                const int m = (slot < c0) ? 0 : 1;
                const int s = m ? (slot - c0) : slot;
                const int j = candIdxS[w][m][s];
                const float* ej = E + (size_t)j * DD;
                double a0 = 0, a1 = 0, a2 = 0, a3 = 0;
#pragma unroll 8
                for (int k = 0; k < DD; k += 4) {
                    const float4 e = *(const float4*)(ej + k);
                    a0 = fma((double)ei[k + 0], (double)e.x, a0);
                    a1 = fma((double)ei[k + 1], (double)e.y, a1);
                    a2 = fma((double)ei[k + 2], (double)e.z, a2);
                    a3 = fma((double)ei[k + 3], (double)e.w, a3);
                }
                candValS[w][m][s] = (a0 + a1) + (a2 + a3);
            }
        }
    }
    __syncthreads();

    // ---- pass 5: rank-based ordered output (ties: lower index first) ----
    if (lane < c0) {
        const double v = candValS[w][0][lane];
        const int idx = candIdxS[w][0][lane];
        int r = 0;
        for (int s = 0; s < c0; ++s) {
            const double o = candValS[w][0][s];
            const int oi = candIdxS[w][0][s];
            r += (o > v) || (o == v && oi < idx);
        }
        if (r >= 1 && r <= 20) knn[i * K_TOT + r - 1] = idx;  // rank0 = self, dropped
    }
    if (lane < c1) {
        const double v = candValS[w][1][lane];
        const int idx = candIdxS[w][1][lane];
        int r = 0;
        for (int s = 0; s < c1; ++s) {
            const double o = candValS[w][1][s];
            const int oi = candIdxS[w][1][s];
            r += (o > v) || (o == v && oi < idx);
        }
        if (r < 10) knn[i * K_TOT + 20 + r] = idx;
    }
}

// ---------------------------------------------------------------------------
// Kernel 3: mutuality + sparse locality scatter + all_close.
// ---------------------------------------------------------------------------
__global__ __launch_bounds__(256) void finalize_k(const int* __restrict__ knn,
                                                  const float* __restrict__ adj,
                                                  const int* __restrict__ cl,
                                                  float* __restrict__ out) {
    const int gid = blockIdx.x * 256 + threadIdx.x;
    if (gid >= NN * K_TOT) return;
    const int i = gid / K_TOT;
    const int j = knn[gid];

    bool mutual = false;
#pragma unroll
    for (int s = 0; s < K_TOT; ++s) mutual |= (knn[j * K_TOT + s] == i);

    if (mutual) out[(size_t)i * NN + j] = adj[(size_t)i * NN + j];

    bool ac = mutual;
    if (!ac) {
        bool alleq = true;
#pragma unroll
        for (int m = 0; m < MM; ++m) alleq &= (cl[m * NN + i] == cl[m * NN + j]);
        ac = alleq;
    }
    out[(size_t)NN * NN + gid] = ac ? 1.0f : 0.0f;
}

// ---------------------------------------------------------------------------
extern "C" void kernel_launch(void* const* d_in, const int* in_sizes, int n_in,
                              void* d_out, int out_size, void* d_ws, size_t ws_size,
                              hipStream_t stream) {
    const float* adj = (const float*)d_in[0];
    const float* enc = (const float*)d_in[1];
    const int* batch = (const int*)d_in[2];
    const int* cl = (const int*)d_in[3];
    float* out = (float*)d_out;

    const size_t simB = (size_t)NN * NN * sizeof(ushort);   // 33.6 MB
    const size_t ebB = (size_t)NN * DD * sizeof(ushort);    // 2.1 MB
    const size_t knnB = (size_t)NN * K_TOT * sizeof(int);   // 0.49 MB

    const dim3 gGrid(NN / 128, NN / 128);

    if (ws_size >= simB + ebB + knnB) {
        ushort* simb = (ushort*)d_ws;
        ushort* Eb = (ushort*)((char*)d_ws + simB);
        int* knn = (int*)((char*)d_ws + simB + ebB);
        hipMemsetAsync(d_out, 0, (size_t)NN * NN * sizeof(float), stream);
        convert_bf16<<<NN * DD / 4 / 256, 256, 0, stream>>>(enc, Eb);
        gemm_bf16<<<gGrid, 256, 0, stream>>>(Eb, simb);
        select_rescore<<<NN / 4, 256, 0, stream>>>(simb, enc, batch, knn);
        finalize_k<<<(NN * K_TOT + 255) / 256, 256, 0, stream>>>(knn, adj, cl, out);
    } else {
        // fallback: stage bf16 sims in the locality region of d_out, memset after
        ushort* simb = (ushort*)d_out;
        ushort* Eb = (ushort*)d_ws;
        int* knn = (int*)((char*)d_ws + ebB);
        convert_bf16<<<NN * DD / 4 / 256, 256, 0, stream>>>(enc, Eb);
        gemm_bf16<<<gGrid, 256, 0, stream>>>(Eb, simb);
        select_rescore<<<NN / 4, 256, 0, stream>>>(simb, enc, batch, knn);
        hipMemsetAsync(d_out, 0, (size_t)NN * NN * sizeof(float), stream);
        finalize_k<<<(NN * K_TOT + 255) / 256, 256, 0, stream>>>(knn, adj, cl, out);
    }
}